// Round 18
// baseline (252.840 us; speedup 1.0000x reference)
//
#include <hip/hip_runtime.h>
#include <math.h>

// MS-SSIM loss, 5 levels, 11-tap separable Gaussian (sigma=1.5), VALID padding.
// Round 18: round-15 body (best, 183us) with two surgical changes:
// 1) loop barrier skipped when tpc<=64 (L2-L4): staging is lane-private, reads
//    are wave-local (in-order DS pipe, r9/r13-validated); cross-wave halo reads
//    only feed cols >= outS (the VALID margin) which are always discarded, so
//    wave drift is provably harmless. Prologue barrier kept.
// 2) one-rcp emit: r = rcp(den_s*den_c); cs = csn*den_s*r; ss = (A+C1)*csn*r
//    (identical algebra, half the quarter-rate transcendentals).
// 4-map transform (a=x+y, b=x-y -> P,Q,U,V), x2-rescaled emit algebra (exact).

struct GWin { float w[11]; };

__global__ __launch_bounds__(256)
void ssim_rows_kernel(const float* __restrict__ X, const float* __restrict__ Y,
                      float* __restrict__ poolX, float* __restrict__ poolY,
                      float* __restrict__ accum,   // [0..95]=ssim, [96..191]=cs
                      int S, int outS, int doPool, int rps, int tpcLog, GWin gw)
{
    __shared__ float4 ab[2][2][264];     // [slot][row01][col-pair unit {a,b,a,b}]

    const int tid = threadIdx.x;
    const int tpc = 1 << tpcLog;         // threads per channel = S/2
    const int lt  = tid & (tpc - 1);
    const int sub = tid >> tpcLog;
    const int ch  = blockIdx.z * (256 >> tpcLog) + sub;
    const int oy0 = blockIdx.x * rps;
    const int halfS = S >> 1;
    const int gc  = 2 * lt;              // thread's base input/output column
    const bool needBar = (tpc > 64);     // block-uniform: L0/L1 barrier, L2-4 free-run

    int rowsOut = outS - oy0; if (rowsOut > rps) rowsOut = rps;
    const int NIT = (rowsOut + 11) >> 1; // iterations (2 input rows each)

    const float* Xc = X + (size_t)ch * S * S;
    const float* Yc = Y + (size_t)ch * S * S;

    float2 sx0, sy0, sx1, sy1;           // prefetched global data (2 rows)

    auto issue = [&](int baseRow) {
        int gr0 = baseRow;     if (gr0 > S - 1) gr0 = S - 1;
        int gr1 = baseRow + 1; if (gr1 > S - 1) gr1 = S - 1;
        sx0 = *reinterpret_cast<const float2*>(Xc + (size_t)gr0 * S + gc);
        sy0 = *reinterpret_cast<const float2*>(Yc + (size_t)gr0 * S + gc);
        sx1 = *reinterpret_cast<const float2*>(Xc + (size_t)gr1 * S + gc);
        sy1 = *reinterpret_cast<const float2*>(Yc + (size_t)gr1 * S + gc);
    };
    auto write_slot = [&](int sl) {      // one b128 per row: {a0,b0,a1,b1}
        ab[sl][0][tid] = make_float4(sx0.x + sy0.x, sx0.x - sy0.x,
                                     sx0.y + sy0.y, sx0.y - sy0.y);
        ab[sl][1][tid] = make_float4(sx1.x + sy1.x, sx1.x - sy1.x,
                                     sx1.y + sy1.y, sx1.y - sy1.y);
    };

    // pending v-conv partials: [col][slot], all static-indexed
    float pendP[2][12], pendQ[2][12], pendU[2][12], pendV[2][12];
    #pragma unroll
    for (int c = 0; c < 2; ++c)
        #pragma unroll
        for (int j = 0; j < 12; ++j) { pendP[c][j] = 0.f; pendQ[c][j] = 0.f; pendU[c][j] = 0.f; pendV[c][j] = 0.f; }

    float ssum = 0.f, csum = 0.f;
    const float C1x2 = 2e-4f, C2x2 = 1.8e-3f;
    const bool ok0 = (gc    ) < outS;
    const bool ok1 = (gc + 1) < outS;

    // prologue (zero the 8 overrun units read by the last threads)
    if (tid < 8) {
        float4 z = make_float4(0.f, 0.f, 0.f, 0.f);
        ab[0][0][256 + tid] = z; ab[0][1][256 + tid] = z;
        ab[1][0][256 + tid] = z; ab[1][1][256 + tid] = z;
    }
    issue(oy0);
    write_slot(0);
    issue(oy0 + 2);
    __syncthreads();                     // prologue barrier always (zero-fill visible)

    for (int k = 0; k < NIT; ++k) {
        const int sl = k & 1;

        // ---- h-conv for both staged rows: 6 ds_read_b128 per row ----
        float hP[2][2], hQ[2][2], hU[2][2], hV[2][2];   // [row][col]
        float4 u0save[2];
        #pragma unroll
        for (int r = 0; r < 2; ++r) {
            const float4* bp = &ab[sl][r][tid];
            float4 u[6];
            #pragma unroll
            for (int i = 0; i < 6; ++i) u[i] = bp[i];
            u0save[r] = u[0];
            const float* v = reinterpret_cast<const float*>(u);  // v[2j]=a_j, v[2j+1]=b_j
            float sqa[12], sqb[12];
            #pragma unroll
            for (int j = 0; j < 12; ++j) {
                float a = v[2 * j], b = v[2 * j + 1];
                sqa[j] = a * a; sqb[j] = b * b;
            }
            float P0 = 0.f, Q0 = 0.f, U0 = 0.f, V0 = 0.f;
            float P1 = 0.f, Q1 = 0.f, U1 = 0.f, V1 = 0.f;
            #pragma unroll
            for (int t = 0; t < 11; ++t) {
                float wt = gw.w[t];
                P0 = fmaf(wt, v[2 * t],     P0);
                Q0 = fmaf(wt, v[2 * t + 1], Q0);
                U0 = fmaf(wt, sqa[t],       U0);
                V0 = fmaf(wt, sqb[t],       V0);
                P1 = fmaf(wt, v[2 * t + 2], P1);
                Q1 = fmaf(wt, v[2 * t + 3], Q1);
                U1 = fmaf(wt, sqa[t + 1],   U1);
                V1 = fmaf(wt, sqb[t + 1],   V1);
            }
            hP[r][0] = P0; hQ[r][0] = Q0; hU[r][0] = U0; hV[r][0] = V0;
            hP[r][1] = P1; hQ[r][1] = Q1; hU[r][1] = U1; hV[r][1] = V1;
        }

        // ---- v-accumulate into pending rings ----
        #pragma unroll
        for (int c = 0; c < 2; ++c) {
            #pragma unroll
            for (int j = 0; j <= 10; ++j) {          // row 2k: w[10-j] -> slot j
                float wt = gw.w[10 - j];
                pendP[c][j] = fmaf(wt, hP[0][c], pendP[c][j]);
                pendQ[c][j] = fmaf(wt, hQ[0][c], pendQ[c][j]);
                pendU[c][j] = fmaf(wt, hU[0][c], pendU[c][j]);
                pendV[c][j] = fmaf(wt, hV[0][c], pendV[c][j]);
            }
            #pragma unroll
            for (int j = 1; j <= 11; ++j) {          // row 2k+1: w[11-j] -> slot j
                float wt = gw.w[11 - j];
                pendP[c][j] = fmaf(wt, hP[1][c], pendP[c][j]);
                pendQ[c][j] = fmaf(wt, hQ[1][c], pendQ[c][j]);
                pendU[c][j] = fmaf(wt, hU[1][c], pendU[c][j]);
                pendV[c][j] = fmaf(wt, hV[1][c], pendV[c][j]);
            }
        }

        // ---- emit 2 finished output rows x 2 cols (one rcp per output) ----
        #pragma unroll
        for (int e = 0; e < 2; ++e) {
            int rel = 2 * k - 10 + e;
            bool rowok = (unsigned)rel < (unsigned)rowsOut;
            #pragma unroll
            for (int c = 0; c < 2; ++c) {
                float p = pendP[c][e], q = pendQ[c][e];
                float uu = pendU[c][e], vv = pendV[c][e];
                float p2 = p * p, q2 = q * q;
                float A = p2 - q2;                       // 2*(2 mu12)
                float csn   = (uu - vv - A) + C2x2;      // 2*(2 sigma12) + 2C2
                float den_c = (uu + vv - p2 - q2) + C2x2;
                float den_s = p2 + q2 + C1x2;
                float r2 = __builtin_amdgcn_rcpf(den_s * den_c);
                float cs = csn * den_s * r2;             // = csn/den_c
                float ss = (A + C1x2) * csn * r2;        // = (A+C1)/den_s * cs
                if (rowok && (c ? ok1 : ok0)) { ssum += ss; csum += cs; }
            }
        }

        // ---- shift rings by 2 slots ----
        #pragma unroll
        for (int c = 0; c < 2; ++c) {
            #pragma unroll
            for (int j = 0; j < 10; ++j) {
                pendP[c][j] = pendP[c][j + 2]; pendQ[c][j] = pendQ[c][j + 2];
                pendU[c][j] = pendU[c][j + 2]; pendV[c][j] = pendV[c][j + 2];
            }
            pendP[c][10] = 0.f; pendP[c][11] = 0.f;
            pendQ[c][10] = 0.f; pendQ[c][11] = 0.f;
            pendU[c][10] = 0.f; pendU[c][11] = 0.f;
            pendV[c][10] = 0.f; pendV[c][11] = 0.f;
        }

        // ---- 2x2 pool from registers (own LDS unit only) ----
        if (doPool && k < (rps >> 1)) {
            float sa = u0save[0].x + u0save[0].z + u0save[1].x + u0save[1].z;
            float sb = u0save[0].y + u0save[0].w + u0save[1].y + u0save[1].w;
            int prow = (oy0 >> 1) + k;
            size_t o = (size_t)ch * halfS * halfS + (size_t)prow * halfS + lt;
            poolX[o] = 0.125f * (sa + sb);
            poolY[o] = 0.125f * (sa - sb);
        }

        // ---- stage next rows (vmcnt drain after all compute) ----
        if (k + 1 < NIT) {
            write_slot(sl ^ 1);
            if (k + 2 < NIT) issue(oy0 + 2 * (k + 2));
        }
        // L0/L1 (tpc>64): cross-wave LDS sharing -> barrier. L2-L4: staging is
        // lane-private & reads wave-local; cross-wave halo only feeds cols>=outS
        // (discarded), so waves may drift freely.
        if (needBar) __syncthreads();
    }

    // ---- per-channel-subgroup reduction + atomic accumulate ----
    {
        int rw = (tpc < 64) ? tpc : 64;
        for (int off = rw >> 1; off > 0; off >>= 1) {
            ssum += __shfl_down(ssum, off);
            csum += __shfl_down(csum, off);
        }
        if ((lt & 63) == 0) {
            atomicAdd(&accum[ch], ssum);
            atomicAdd(&accum[96 + ch], csum);
        }
    }
}

__global__ void finalize_kernel(const float* __restrict__ accum, float* __restrict__ out)
{
    __shared__ float red[2];
    const int t = threadIdx.x;   // 128 threads
    const float w[5]   = {0.0448f, 0.2856f, 0.3001f, 0.2363f, 0.1333f};
    const float inv[5] = {1.f / (502.f * 502.f), 1.f / (246.f * 246.f),
                          1.f / (118.f * 118.f), 1.f / (54.f * 54.f),
                          1.f / (22.f * 22.f)};
    float ms = 0.f;
    if (t < 96) {
        ms = 1.f;
        #pragma unroll
        for (int l = 0; l < 5; ++l) {
            float v = (l < 4) ? accum[l * 192 + 96 + t] : accum[l * 192 + t];
            v *= inv[l];
            v = fmaxf(v, 0.f);
            ms *= powf(v, w[l]);
        }
    }
    for (int off = 32; off > 0; off >>= 1) ms += __shfl_down(ms, off);
    int wid = t >> 6, lane = t & 63;
    if (lane == 0) red[wid] = ms;
    __syncthreads();
    if (t == 0) out[0] = 1.f - (red[0] + red[1]) * (1.f / 96.f);
}

extern "C" void kernel_launch(void* const* d_in, const int* in_sizes, int n_in,
                              void* d_out, int out_size, void* d_ws, size_t ws_size,
                              hipStream_t stream)
{
    (void)in_sizes; (void)n_in; (void)out_size; (void)ws_size;
    const float* X = (const float*)d_in[0];
    const float* Y = (const float*)d_in[1];
    float* out = (float*)d_out;
    float* ws  = (float*)d_ws;

    // Gaussian window (size 11, sigma 1.5), normalized
    GWin gw;
    {
        double g[11], s = 0.0;
        for (int i = 0; i < 11; ++i) { double d = i - 5; g[i] = exp(-(d * d) / 4.5); s += g[i]; }
        for (int i = 0; i < 11; ++i) gw.w[i] = (float)(g[i] / s);
    }

    // workspace layout (floats)
    float* accum = ws;                 // 5 levels * 192
    size_t off = 1024;
    float* p1x = ws + off; off += (size_t)96 * 256 * 256;
    float* p1y = ws + off; off += (size_t)96 * 256 * 256;
    float* p2x = ws + off; off += (size_t)96 * 128 * 128;
    float* p2y = ws + off; off += (size_t)96 * 128 * 128;
    float* p3x = ws + off; off += (size_t)96 * 64 * 64;
    float* p3y = ws + off; off += (size_t)96 * 64 * 64;
    float* p4x = ws + off; off += (size_t)96 * 32 * 32;
    float* p4y = ws + off; off += (size_t)96 * 32 * 32;

    hipMemsetAsync(accum, 0, 5 * 192 * sizeof(float), stream);

    auto launch = [&](const float* x, const float* y, float* px_, float* py_,
                      float* acc, int S, int outS, int pool, int rps, int tpcLog) {
        int nsub = 256 >> tpcLog;
        dim3 g((outS + rps - 1) / rps, 1, 96 / nsub);
        ssim_rows_kernel<<<g, 256, 0, stream>>>(x, y, px_, py_, acc, S, outS, pool,
                                                rps, tpcLog, gw);
    };

    // r15 grids exactly (best measured): tpc = S/2 threads per channel
    launch(X,   Y,   p1x, p1y, accum + 0,   512, 502, 1, 64, 8);  // 8 strips x 96
    launch(p1x, p1y, p2x, p2y, accum + 192, 256, 246, 1, 32, 7);  // 8 x 48
    launch(p2x, p2y, p3x, p3y, accum + 384, 128, 118, 1, 16, 6);  // 8 x 24
    launch(p3x, p3y, p4x, p4y, accum + 576, 64,  54,  1, 16, 5);  // 4 x 12
    launch(p4x, p4y, nullptr, nullptr, accum + 768, 32, 22, 0, 22, 4);  // 1 x 6

    finalize_kernel<<<1, 128, 0, stream>>>(accum, out);
}

// Round 19
// 163.414 us; speedup vs baseline: 1.5472x; 1.5472x over previous
//
#include <hip/hip_runtime.h>
#include <math.h>

// MS-SSIM loss, 5 levels, 11-tap separable Gaussian (sigma=1.5), VALID padding.
// Round 19: pyramid de-serialization. Level-0 kernel (r15 body) builds the FULL
// pool pyramid P1..P4 in-strip via parity-carried registers + shfl_xor butterfly
// (pooling is linear in (a,b)-domain and associative). Levels 1..4 then become
// mutually independent and run as ONE fused 630-block dispatch (level decoded
// from flat blockIdx with ternaries), so L2-L4 hide under L1 instead of running
// serially at <2 blocks/CU each.
// 4-map transform (a=x+y, b=x-y -> P,Q,U,V), x2-rescaled emit algebra (exact).

struct GWin { float w[11]; };

// ---------------- Level-0 kernel: SSIM(L0) + full pyramid ----------------
__global__ __launch_bounds__(256)
void ssim_l0_kernel(const float* __restrict__ X, const float* __restrict__ Y,
                    float* __restrict__ p1x, float* __restrict__ p1y,
                    float* __restrict__ p2x, float* __restrict__ p2y,
                    float* __restrict__ p3x, float* __restrict__ p3y,
                    float* __restrict__ p4x, float* __restrict__ p4y,
                    float* __restrict__ accum, GWin gw)
{
    const int S = 512, outS = 502, rps = 64;
    __shared__ float4 ab[2][2][264];

    const int tid = threadIdx.x;
    const int ch  = blockIdx.z;
    const int oy0 = blockIdx.x * rps;
    const int gc  = 2 * tid;

    int rowsOut = outS - oy0; if (rowsOut > rps) rowsOut = rps;
    const int NIT = (rowsOut + 11) >> 1;

    const float* Xc = X + (size_t)ch * S * S;
    const float* Yc = Y + (size_t)ch * S * S;

    float2 sx0, sy0, sx1, sy1;

    auto issue = [&](int baseRow) {
        int gr0 = baseRow;     if (gr0 > S - 1) gr0 = S - 1;
        int gr1 = baseRow + 1; if (gr1 > S - 1) gr1 = S - 1;
        sx0 = *reinterpret_cast<const float2*>(Xc + (size_t)gr0 * S + gc);
        sy0 = *reinterpret_cast<const float2*>(Yc + (size_t)gr0 * S + gc);
        sx1 = *reinterpret_cast<const float2*>(Xc + (size_t)gr1 * S + gc);
        sy1 = *reinterpret_cast<const float2*>(Yc + (size_t)gr1 * S + gc);
    };
    auto write_slot = [&](int sl) {
        ab[sl][0][tid] = make_float4(sx0.x + sy0.x, sx0.x - sy0.x,
                                     sx0.y + sy0.y, sx0.y - sy0.y);
        ab[sl][1][tid] = make_float4(sx1.x + sy1.x, sx1.x - sy1.x,
                                     sx1.y + sy1.y, sx1.y - sy1.y);
    };

    float pendP[2][12], pendQ[2][12], pendU[2][12], pendV[2][12];
    #pragma unroll
    for (int c = 0; c < 2; ++c)
        #pragma unroll
        for (int j = 0; j < 12; ++j) { pendP[c][j] = 0.f; pendQ[c][j] = 0.f; pendU[c][j] = 0.f; pendV[c][j] = 0.f; }

    float ssum = 0.f, csum = 0.f;
    const float C1x2 = 2e-4f, C2x2 = 1.8e-3f;
    const bool ok0 = gc < outS, ok1 = (gc + 1) < outS;

    float c1a = 0.f, c1b = 0.f, c2a = 0.f, c2b = 0.f, c3a = 0.f, c3b = 0.f;  // pyramid carries

    if (tid < 8) {
        float4 z = make_float4(0.f, 0.f, 0.f, 0.f);
        ab[0][0][256 + tid] = z; ab[0][1][256 + tid] = z;
        ab[1][0][256 + tid] = z; ab[1][1][256 + tid] = z;
    }
    issue(oy0);
    write_slot(0);
    issue(oy0 + 2);
    __syncthreads();

    for (int k = 0; k < NIT; ++k) {
        const int sl = k & 1;

        float hP[2][2], hQ[2][2], hU[2][2], hV[2][2];
        float4 u0save[2];
        #pragma unroll
        for (int r = 0; r < 2; ++r) {
            const float4* bp = &ab[sl][r][tid];
            float4 u[6];
            #pragma unroll
            for (int i = 0; i < 6; ++i) u[i] = bp[i];
            u0save[r] = u[0];
            const float* v = reinterpret_cast<const float*>(u);
            float sqa[12], sqb[12];
            #pragma unroll
            for (int j = 0; j < 12; ++j) {
                float a = v[2 * j], b = v[2 * j + 1];
                sqa[j] = a * a; sqb[j] = b * b;
            }
            float P0 = 0.f, Q0 = 0.f, U0 = 0.f, V0 = 0.f;
            float P1 = 0.f, Q1 = 0.f, U1 = 0.f, V1 = 0.f;
            #pragma unroll
            for (int t = 0; t < 11; ++t) {
                float wt = gw.w[t];
                P0 = fmaf(wt, v[2 * t],     P0);
                Q0 = fmaf(wt, v[2 * t + 1], Q0);
                U0 = fmaf(wt, sqa[t],       U0);
                V0 = fmaf(wt, sqb[t],       V0);
                P1 = fmaf(wt, v[2 * t + 2], P1);
                Q1 = fmaf(wt, v[2 * t + 3], Q1);
                U1 = fmaf(wt, sqa[t + 1],   U1);
                V1 = fmaf(wt, sqb[t + 1],   V1);
            }
            hP[r][0] = P0; hQ[r][0] = Q0; hU[r][0] = U0; hV[r][0] = V0;
            hP[r][1] = P1; hQ[r][1] = Q1; hU[r][1] = U1; hV[r][1] = V1;
        }

        #pragma unroll
        for (int c = 0; c < 2; ++c) {
            #pragma unroll
            for (int j = 0; j <= 10; ++j) {
                float wt = gw.w[10 - j];
                pendP[c][j] = fmaf(wt, hP[0][c], pendP[c][j]);
                pendQ[c][j] = fmaf(wt, hQ[0][c], pendQ[c][j]);
                pendU[c][j] = fmaf(wt, hU[0][c], pendU[c][j]);
                pendV[c][j] = fmaf(wt, hV[0][c], pendV[c][j]);
            }
            #pragma unroll
            for (int j = 1; j <= 11; ++j) {
                float wt = gw.w[11 - j];
                pendP[c][j] = fmaf(wt, hP[1][c], pendP[c][j]);
                pendQ[c][j] = fmaf(wt, hQ[1][c], pendQ[c][j]);
                pendU[c][j] = fmaf(wt, hU[1][c], pendU[c][j]);
                pendV[c][j] = fmaf(wt, hV[1][c], pendV[c][j]);
            }
        }

        #pragma unroll
        for (int e = 0; e < 2; ++e) {
            int rel = 2 * k - 10 + e;
            bool rowok = (unsigned)rel < (unsigned)rowsOut;
            #pragma unroll
            for (int c = 0; c < 2; ++c) {
                float p = pendP[c][e], q = pendQ[c][e];
                float uu = pendU[c][e], vv = pendV[c][e];
                float p2 = p * p, q2 = q * q;
                float A = p2 - q2;
                float csn = (uu - vv - A) + C2x2;
                float csd = (uu + vv - p2 - q2) + C2x2;
                float cs  = csn * __builtin_amdgcn_rcpf(csd);
                float ss  = (A + C1x2) * __builtin_amdgcn_rcpf(p2 + q2 + C1x2) * cs;
                if (rowok && (c ? ok1 : ok0)) { ssum += ss; csum += cs; }
            }
        }

        #pragma unroll
        for (int c = 0; c < 2; ++c) {
            #pragma unroll
            for (int j = 0; j < 10; ++j) {
                pendP[c][j] = pendP[c][j + 2]; pendQ[c][j] = pendQ[c][j + 2];
                pendU[c][j] = pendU[c][j + 2]; pendV[c][j] = pendV[c][j + 2];
            }
            pendP[c][10] = 0.f; pendP[c][11] = 0.f;
            pendQ[c][10] = 0.f; pendQ[c][11] = 0.f;
            pendU[c][10] = 0.f; pendU[c][11] = 0.f;
            pendV[c][10] = 0.f; pendV[c][11] = 0.f;
        }

        // ---- pyramid: P1 direct; P2/P3/P4 via parity carries + shfl_xor ----
        if (k < 32) {
            float p1a = 0.25f * (u0save[0].x + u0save[0].z + u0save[1].x + u0save[1].z);
            float p1b = 0.25f * (u0save[0].y + u0save[0].w + u0save[1].y + u0save[1].w);
            {
                int prow = (oy0 >> 1) + k;
                size_t o = (size_t)ch * 256 * 256 + (size_t)prow * 256 + tid;
                p1x[o] = 0.5f * (p1a + p1b);
                p1y[o] = 0.5f * (p1a - p1b);
            }
            if ((k & 1) == 0) { c1a = p1a; c1b = p1b; }
            else {
                float ta = c1a + p1a, tb = c1b + p1b;
                float p2a = 0.25f * (ta + __shfl_xor(ta, 1));
                float p2b = 0.25f * (tb + __shfl_xor(tb, 1));
                if ((tid & 1) == 0) {
                    int r2 = (oy0 >> 2) + (k >> 1);
                    size_t o = (size_t)ch * 128 * 128 + (size_t)r2 * 128 + (tid >> 1);
                    p2x[o] = 0.5f * (p2a + p2b);
                    p2y[o] = 0.5f * (p2a - p2b);
                }
                if (((k >> 1) & 1) == 0) { c2a = p2a; c2b = p2b; }
                else {
                    float t3a = c2a + p2a, t3b = c2b + p2b;
                    float p3a = 0.25f * (t3a + __shfl_xor(t3a, 2));
                    float p3b = 0.25f * (t3b + __shfl_xor(t3b, 2));
                    if ((tid & 3) == 0) {
                        int r3 = (oy0 >> 3) + (k >> 2);
                        size_t o = (size_t)ch * 64 * 64 + (size_t)r3 * 64 + (tid >> 2);
                        p3x[o] = 0.5f * (p3a + p3b);
                        p3y[o] = 0.5f * (p3a - p3b);
                    }
                    if (((k >> 2) & 1) == 0) { c3a = p3a; c3b = p3b; }
                    else {
                        float t4a = c3a + p3a, t4b = c3b + p3b;
                        float p4a = 0.25f * (t4a + __shfl_xor(t4a, 4));
                        float p4b = 0.25f * (t4b + __shfl_xor(t4b, 4));
                        if ((tid & 7) == 0) {
                            int r4 = (oy0 >> 4) + (k >> 3);
                            size_t o = (size_t)ch * 32 * 32 + (size_t)r4 * 32 + (tid >> 3);
                            p4x[o] = 0.5f * (p4a + p4b);
                            p4y[o] = 0.5f * (p4a - p4b);
                        }
                    }
                }
            }
        }

        if (k + 1 < NIT) {
            write_slot(sl ^ 1);
            if (k + 2 < NIT) issue(oy0 + 2 * (k + 2));
        }
        __syncthreads();
    }

    for (int off = 32; off > 0; off >>= 1) {
        ssum += __shfl_down(ssum, off);
        csum += __shfl_down(csum, off);
    }
    if ((tid & 63) == 0) {
        atomicAdd(&accum[ch], ssum);
        atomicAdd(&accum[96 + ch], csum);
    }
}

// ------------- Fused levels 1..4 kernel (no pooling, 630 blocks) -------------
__global__ __launch_bounds__(256)
void ssim_rest_kernel(const float* __restrict__ x1, const float* __restrict__ y1,
                      const float* __restrict__ x2, const float* __restrict__ y2,
                      const float* __restrict__ x3, const float* __restrict__ y3,
                      const float* __restrict__ x4, const float* __restrict__ y4,
                      float* __restrict__ accum, GWin gw)
{
    __shared__ float4 ab[2][2][264];

    const int bid = blockIdx.x;
    const int L = (bid >= 624) ? 3 : (bid >= 576) ? 2 : (bid >= 384) ? 1 : 0;
    const int off0 = (L == 0) ? 0 : (L == 1) ? 384 : (L == 2) ? 576 : 624;
    const int r = bid - off0;

    const int S      = (L == 0) ? 256 : (L == 1) ? 128 : (L == 2) ? 64 : 32;
    const int outS   = (L == 0) ? 246 : (L == 1) ? 118 : (L == 2) ? 54 : 22;
    const int rps    = (L == 0) ? 32  : (L == 1) ? 16  : (L == 2) ? 16 : 22;
    const int tpcLog = (L == 0) ? 7   : (L == 1) ? 6   : (L == 2) ? 5  : 4;
    const int stripsLog = (L == 0) ? 3 : (L == 1) ? 3 : (L == 2) ? 2 : 0;
    const float* Xl = (L == 0) ? x1 : (L == 1) ? x2 : (L == 2) ? x3 : x4;
    const float* Yl = (L == 0) ? y1 : (L == 1) ? y2 : (L == 2) ? y3 : y4;
    float* acc = accum + 192 * (L + 1);

    const int zidx  = r >> stripsLog;
    const int strip = r & ((1 << stripsLog) - 1);

    const int tid = threadIdx.x;
    const int tpc = 1 << tpcLog;
    const int lt  = tid & (tpc - 1);
    const int sub = tid >> tpcLog;
    const int ch  = zidx * (256 >> tpcLog) + sub;
    const int oy0 = strip * rps;
    const int gc  = 2 * lt;

    int rowsOut = outS - oy0; if (rowsOut > rps) rowsOut = rps;
    const int NIT = (rowsOut + 11) >> 1;

    const float* Xc = Xl + (size_t)ch * S * S;
    const float* Yc = Yl + (size_t)ch * S * S;

    float2 sx0, sy0, sx1, sy1;

    auto issue = [&](int baseRow) {
        int gr0 = baseRow;     if (gr0 > S - 1) gr0 = S - 1;
        int gr1 = baseRow + 1; if (gr1 > S - 1) gr1 = S - 1;
        sx0 = *reinterpret_cast<const float2*>(Xc + (size_t)gr0 * S + gc);
        sy0 = *reinterpret_cast<const float2*>(Yc + (size_t)gr0 * S + gc);
        sx1 = *reinterpret_cast<const float2*>(Xc + (size_t)gr1 * S + gc);
        sy1 = *reinterpret_cast<const float2*>(Yc + (size_t)gr1 * S + gc);
    };
    auto write_slot = [&](int sl) {
        ab[sl][0][tid] = make_float4(sx0.x + sy0.x, sx0.x - sy0.x,
                                     sx0.y + sy0.y, sx0.y - sy0.y);
        ab[sl][1][tid] = make_float4(sx1.x + sy1.x, sx1.x - sy1.x,
                                     sx1.y + sy1.y, sx1.y - sy1.y);
    };

    float pendP[2][12], pendQ[2][12], pendU[2][12], pendV[2][12];
    #pragma unroll
    for (int c = 0; c < 2; ++c)
        #pragma unroll
        for (int j = 0; j < 12; ++j) { pendP[c][j] = 0.f; pendQ[c][j] = 0.f; pendU[c][j] = 0.f; pendV[c][j] = 0.f; }

    float ssum = 0.f, csum = 0.f;
    const float C1x2 = 2e-4f, C2x2 = 1.8e-3f;
    const bool ok0 = gc < outS, ok1 = (gc + 1) < outS;

    if (tid < 8) {
        float4 z = make_float4(0.f, 0.f, 0.f, 0.f);
        ab[0][0][256 + tid] = z; ab[0][1][256 + tid] = z;
        ab[1][0][256 + tid] = z; ab[1][1][256 + tid] = z;
    }
    issue(oy0);
    write_slot(0);
    issue(oy0 + 2);
    __syncthreads();

    for (int k = 0; k < NIT; ++k) {
        const int sl = k & 1;

        float hP[2][2], hQ[2][2], hU[2][2], hV[2][2];
        #pragma unroll
        for (int r2 = 0; r2 < 2; ++r2) {
            const float4* bp = &ab[sl][r2][tid];
            float4 u[6];
            #pragma unroll
            for (int i = 0; i < 6; ++i) u[i] = bp[i];
            const float* v = reinterpret_cast<const float*>(u);
            float sqa[12], sqb[12];
            #pragma unroll
            for (int j = 0; j < 12; ++j) {
                float a = v[2 * j], b = v[2 * j + 1];
                sqa[j] = a * a; sqb[j] = b * b;
            }
            float P0 = 0.f, Q0 = 0.f, U0 = 0.f, V0 = 0.f;
            float P1 = 0.f, Q1 = 0.f, U1 = 0.f, V1 = 0.f;
            #pragma unroll
            for (int t = 0; t < 11; ++t) {
                float wt = gw.w[t];
                P0 = fmaf(wt, v[2 * t],     P0);
                Q0 = fmaf(wt, v[2 * t + 1], Q0);
                U0 = fmaf(wt, sqa[t],       U0);
                V0 = fmaf(wt, sqb[t],       V0);
                P1 = fmaf(wt, v[2 * t + 2], P1);
                Q1 = fmaf(wt, v[2 * t + 3], Q1);
                U1 = fmaf(wt, sqa[t + 1],   U1);
                V1 = fmaf(wt, sqb[t + 1],   V1);
            }
            hP[r2][0] = P0; hQ[r2][0] = Q0; hU[r2][0] = U0; hV[r2][0] = V0;
            hP[r2][1] = P1; hQ[r2][1] = Q1; hU[r2][1] = U1; hV[r2][1] = V1;
        }

        #pragma unroll
        for (int c = 0; c < 2; ++c) {
            #pragma unroll
            for (int j = 0; j <= 10; ++j) {
                float wt = gw.w[10 - j];
                pendP[c][j] = fmaf(wt, hP[0][c], pendP[c][j]);
                pendQ[c][j] = fmaf(wt, hQ[0][c], pendQ[c][j]);
                pendU[c][j] = fmaf(wt, hU[0][c], pendU[c][j]);
                pendV[c][j] = fmaf(wt, hV[0][c], pendV[c][j]);
            }
            #pragma unroll
            for (int j = 1; j <= 11; ++j) {
                float wt = gw.w[11 - j];
                pendP[c][j] = fmaf(wt, hP[1][c], pendP[c][j]);
                pendQ[c][j] = fmaf(wt, hQ[1][c], pendQ[c][j]);
                pendU[c][j] = fmaf(wt, hU[1][c], pendU[c][j]);
                pendV[c][j] = fmaf(wt, hV[1][c], pendV[c][j]);
            }
        }

        #pragma unroll
        for (int e = 0; e < 2; ++e) {
            int rel = 2 * k - 10 + e;
            bool rowok = (unsigned)rel < (unsigned)rowsOut;
            #pragma unroll
            for (int c = 0; c < 2; ++c) {
                float p = pendP[c][e], q = pendQ[c][e];
                float uu = pendU[c][e], vv = pendV[c][e];
                float p2 = p * p, q2 = q * q;
                float A = p2 - q2;
                float csn = (uu - vv - A) + C2x2;
                float csd = (uu + vv - p2 - q2) + C2x2;
                float cs  = csn * __builtin_amdgcn_rcpf(csd);
                float ss  = (A + C1x2) * __builtin_amdgcn_rcpf(p2 + q2 + C1x2) * cs;
                if (rowok && (c ? ok1 : ok0)) { ssum += ss; csum += cs; }
            }
        }

        #pragma unroll
        for (int c = 0; c < 2; ++c) {
            #pragma unroll
            for (int j = 0; j < 10; ++j) {
                pendP[c][j] = pendP[c][j + 2]; pendQ[c][j] = pendQ[c][j + 2];
                pendU[c][j] = pendU[c][j + 2]; pendV[c][j] = pendV[c][j + 2];
            }
            pendP[c][10] = 0.f; pendP[c][11] = 0.f;
            pendQ[c][10] = 0.f; pendQ[c][11] = 0.f;
            pendU[c][10] = 0.f; pendU[c][11] = 0.f;
            pendV[c][10] = 0.f; pendV[c][11] = 0.f;
        }

        if (k + 1 < NIT) {
            write_slot(sl ^ 1);
            if (k + 2 < NIT) issue(oy0 + 2 * (k + 2));
        }
        __syncthreads();
    }

    {
        int rw = (tpc < 64) ? tpc : 64;
        for (int off = rw >> 1; off > 0; off >>= 1) {
            ssum += __shfl_down(ssum, off);
            csum += __shfl_down(csum, off);
        }
        if ((lt & 63) == 0) {
            atomicAdd(&acc[ch], ssum);
            atomicAdd(&acc[96 + ch], csum);
        }
    }
}

__global__ void finalize_kernel(const float* __restrict__ accum, float* __restrict__ out)
{
    __shared__ float red[2];
    const int t = threadIdx.x;   // 128 threads
    const float w[5]   = {0.0448f, 0.2856f, 0.3001f, 0.2363f, 0.1333f};
    const float inv[5] = {1.f / (502.f * 502.f), 1.f / (246.f * 246.f),
                          1.f / (118.f * 118.f), 1.f / (54.f * 54.f),
                          1.f / (22.f * 22.f)};
    float ms = 0.f;
    if (t < 96) {
        ms = 1.f;
        #pragma unroll
        for (int l = 0; l < 5; ++l) {
            float v = (l < 4) ? accum[l * 192 + 96 + t] : accum[l * 192 + t];
            v *= inv[l];
            v = fmaxf(v, 0.f);
            ms *= powf(v, w[l]);
        }
    }
    for (int off = 32; off > 0; off >>= 1) ms += __shfl_down(ms, off);
    int wid = t >> 6, lane = t & 63;
    if (lane == 0) red[wid] = ms;
    __syncthreads();
    if (t == 0) out[0] = 1.f - (red[0] + red[1]) * (1.f / 96.f);
}

extern "C" void kernel_launch(void* const* d_in, const int* in_sizes, int n_in,
                              void* d_out, int out_size, void* d_ws, size_t ws_size,
                              hipStream_t stream)
{
    (void)in_sizes; (void)n_in; (void)out_size; (void)ws_size;
    const float* X = (const float*)d_in[0];
    const float* Y = (const float*)d_in[1];
    float* out = (float*)d_out;
    float* ws  = (float*)d_ws;

    // Gaussian window (size 11, sigma 1.5), normalized
    GWin gw;
    {
        double g[11], s = 0.0;
        for (int i = 0; i < 11; ++i) { double d = i - 5; g[i] = exp(-(d * d) / 4.5); s += g[i]; }
        for (int i = 0; i < 11; ++i) gw.w[i] = (float)(g[i] / s);
    }

    // workspace layout (floats): accum then pyramid buffers
    float* accum = ws;                 // 5 levels * 192 (L0 at +0, L1..L4 at +192*(L+1))
    size_t off = 1024;
    float* p1x = ws + off; off += (size_t)96 * 256 * 256;
    float* p1y = ws + off; off += (size_t)96 * 256 * 256;
    float* p2x = ws + off; off += (size_t)96 * 128 * 128;
    float* p2y = ws + off; off += (size_t)96 * 128 * 128;
    float* p3x = ws + off; off += (size_t)96 * 64 * 64;
    float* p3y = ws + off; off += (size_t)96 * 64 * 64;
    float* p4x = ws + off; off += (size_t)96 * 32 * 32;
    float* p4y = ws + off; off += (size_t)96 * 32 * 32;

    hipMemsetAsync(accum, 0, 5 * 192 * sizeof(float), stream);

    // L0: SSIM + full pyramid (8 strips x 96 channels)
    ssim_l0_kernel<<<dim3(8, 1, 96), 256, 0, stream>>>(
        X, Y, p1x, p1y, p2x, p2y, p3x, p3y, p4x, p4y, accum, gw);

    // L1..L4 fused: 384 + 192 + 48 + 6 = 630 blocks
    ssim_rest_kernel<<<dim3(630), 256, 0, stream>>>(
        p1x, p1y, p2x, p2y, p3x, p3y, p4x, p4y, accum, gw);

    finalize_kernel<<<1, 128, 0, stream>>>(accum, out);
}

// Round 20
// 149.707 us; speedup vs baseline: 1.6889x; 1.0916x over previous
//
#include <hip/hip_runtime.h>
#include <math.h>

// MS-SSIM loss, 5 levels, 11-tap separable Gaussian (sigma=1.5), VALID padding.
// Round 20: keep r19's pyramid de-serialization but move P2..P4 production OUT
// of the L0 kernel (which regressed 104->128us at VGPR 104) into a tiny
// hierarchical pool kernel. Pipeline:
//   L0 (r15 body verbatim, 84 VGPR, writes P1) ->
//   pool_pyramid (P1 -> P2,P3,P4; 16x96 blocks, shfl butterflies) ->
//   fused rest kernel (L1..L4, 630 blocks) -> finalize.
// 4-map transform (a=x+y, b=x-y -> P,Q,U,V), x2-rescaled emit algebra (exact).

struct GWin { float w[11]; };

// ---------------- r15 row-streaming SSIM kernel (L0 only here) ----------------
__global__ __launch_bounds__(256)
void ssim_rows_kernel(const float* __restrict__ X, const float* __restrict__ Y,
                      float* __restrict__ poolX, float* __restrict__ poolY,
                      float* __restrict__ accum,   // [0..95]=ssim, [96..191]=cs
                      int S, int outS, int doPool, int rps, int tpcLog, GWin gw)
{
    __shared__ float4 ab[2][2][264];     // [slot][row01][col-pair unit {a,b,a,b}]

    const int tid = threadIdx.x;
    const int tpc = 1 << tpcLog;         // threads per channel = S/2
    const int lt  = tid & (tpc - 1);
    const int sub = tid >> tpcLog;
    const int ch  = blockIdx.z * (256 >> tpcLog) + sub;
    const int oy0 = blockIdx.x * rps;
    const int halfS = S >> 1;
    const int gc  = 2 * lt;              // thread's base input/output column

    int rowsOut = outS - oy0; if (rowsOut > rps) rowsOut = rps;
    const int NIT = (rowsOut + 11) >> 1; // iterations (2 input rows each)

    const float* Xc = X + (size_t)ch * S * S;
    const float* Yc = Y + (size_t)ch * S * S;

    float2 sx0, sy0, sx1, sy1;           // prefetched global data (2 rows)

    auto issue = [&](int baseRow) {
        int gr0 = baseRow;     if (gr0 > S - 1) gr0 = S - 1;
        int gr1 = baseRow + 1; if (gr1 > S - 1) gr1 = S - 1;
        sx0 = *reinterpret_cast<const float2*>(Xc + (size_t)gr0 * S + gc);
        sy0 = *reinterpret_cast<const float2*>(Yc + (size_t)gr0 * S + gc);
        sx1 = *reinterpret_cast<const float2*>(Xc + (size_t)gr1 * S + gc);
        sy1 = *reinterpret_cast<const float2*>(Yc + (size_t)gr1 * S + gc);
    };
    auto write_slot = [&](int sl) {      // one b128 per row: {a0,b0,a1,b1}
        ab[sl][0][tid] = make_float4(sx0.x + sy0.x, sx0.x - sy0.x,
                                     sx0.y + sy0.y, sx0.y - sy0.y);
        ab[sl][1][tid] = make_float4(sx1.x + sy1.x, sx1.x - sy1.x,
                                     sx1.y + sy1.y, sx1.y - sy1.y);
    };

    // pending v-conv partials: [col][slot], all static-indexed
    float pendP[2][12], pendQ[2][12], pendU[2][12], pendV[2][12];
    #pragma unroll
    for (int c = 0; c < 2; ++c)
        #pragma unroll
        for (int j = 0; j < 12; ++j) { pendP[c][j] = 0.f; pendQ[c][j] = 0.f; pendU[c][j] = 0.f; pendV[c][j] = 0.f; }

    float ssum = 0.f, csum = 0.f;
    const float C1x2 = 2e-4f, C2x2 = 1.8e-3f;
    const bool ok0 = (gc    ) < outS;
    const bool ok1 = (gc + 1) < outS;

    // prologue (zero the 8 overrun units read by the last threads)
    if (tid < 8) {
        float4 z = make_float4(0.f, 0.f, 0.f, 0.f);
        ab[0][0][256 + tid] = z; ab[0][1][256 + tid] = z;
        ab[1][0][256 + tid] = z; ab[1][1][256 + tid] = z;
    }
    issue(oy0);
    write_slot(0);
    issue(oy0 + 2);
    __syncthreads();

    for (int k = 0; k < NIT; ++k) {
        const int sl = k & 1;

        // ---- h-conv for both staged rows: 6 ds_read_b128 per row ----
        float hP[2][2], hQ[2][2], hU[2][2], hV[2][2];   // [row][col]
        float4 u0save[2];
        #pragma unroll
        for (int r = 0; r < 2; ++r) {
            const float4* bp = &ab[sl][r][tid];
            float4 u[6];
            #pragma unroll
            for (int i = 0; i < 6; ++i) u[i] = bp[i];
            u0save[r] = u[0];
            const float* v = reinterpret_cast<const float*>(u);  // v[2j]=a_j, v[2j+1]=b_j
            float sqa[12], sqb[12];
            #pragma unroll
            for (int j = 0; j < 12; ++j) {
                float a = v[2 * j], b = v[2 * j + 1];
                sqa[j] = a * a; sqb[j] = b * b;
            }
            float P0 = 0.f, Q0 = 0.f, U0 = 0.f, V0 = 0.f;
            float P1 = 0.f, Q1 = 0.f, U1 = 0.f, V1 = 0.f;
            #pragma unroll
            for (int t = 0; t < 11; ++t) {
                float wt = gw.w[t];
                P0 = fmaf(wt, v[2 * t],     P0);
                Q0 = fmaf(wt, v[2 * t + 1], Q0);
                U0 = fmaf(wt, sqa[t],       U0);
                V0 = fmaf(wt, sqb[t],       V0);
                P1 = fmaf(wt, v[2 * t + 2], P1);
                Q1 = fmaf(wt, v[2 * t + 3], Q1);
                U1 = fmaf(wt, sqa[t + 1],   U1);
                V1 = fmaf(wt, sqb[t + 1],   V1);
            }
            hP[r][0] = P0; hQ[r][0] = Q0; hU[r][0] = U0; hV[r][0] = V0;
            hP[r][1] = P1; hQ[r][1] = Q1; hU[r][1] = U1; hV[r][1] = V1;
        }

        // ---- v-accumulate into pending rings ----
        #pragma unroll
        for (int c = 0; c < 2; ++c) {
            #pragma unroll
            for (int j = 0; j <= 10; ++j) {          // row 2k: w[10-j] -> slot j
                float wt = gw.w[10 - j];
                pendP[c][j] = fmaf(wt, hP[0][c], pendP[c][j]);
                pendQ[c][j] = fmaf(wt, hQ[0][c], pendQ[c][j]);
                pendU[c][j] = fmaf(wt, hU[0][c], pendU[c][j]);
                pendV[c][j] = fmaf(wt, hV[0][c], pendV[c][j]);
            }
            #pragma unroll
            for (int j = 1; j <= 11; ++j) {          // row 2k+1: w[11-j] -> slot j
                float wt = gw.w[11 - j];
                pendP[c][j] = fmaf(wt, hP[1][c], pendP[c][j]);
                pendQ[c][j] = fmaf(wt, hQ[1][c], pendQ[c][j]);
                pendU[c][j] = fmaf(wt, hU[1][c], pendU[c][j]);
                pendV[c][j] = fmaf(wt, hV[1][c], pendV[c][j]);
            }
        }

        // ---- emit 2 finished output rows x 2 cols (x2-rescaled, exact) ----
        #pragma unroll
        for (int e = 0; e < 2; ++e) {
            int rel = 2 * k - 10 + e;
            bool rowok = (unsigned)rel < (unsigned)rowsOut;
            #pragma unroll
            for (int c = 0; c < 2; ++c) {
                float p = pendP[c][e], q = pendQ[c][e];
                float uu = pendU[c][e], vv = pendV[c][e];
                float p2 = p * p, q2 = q * q;
                float A = p2 - q2;                       // 2*(2 mu12)
                float csn = (uu - vv - A) + C2x2;        // 2*(2 sigma12) + 2C2
                float csd = (uu + vv - p2 - q2) + C2x2;
                float cs  = csn * __builtin_amdgcn_rcpf(csd);
                float ss  = (A + C1x2) * __builtin_amdgcn_rcpf(p2 + q2 + C1x2) * cs;
                if (rowok && (c ? ok1 : ok0)) { ssum += ss; csum += cs; }
            }
        }

        // ---- shift rings by 2 slots ----
        #pragma unroll
        for (int c = 0; c < 2; ++c) {
            #pragma unroll
            for (int j = 0; j < 10; ++j) {
                pendP[c][j] = pendP[c][j + 2]; pendQ[c][j] = pendQ[c][j + 2];
                pendU[c][j] = pendU[c][j + 2]; pendV[c][j] = pendV[c][j + 2];
            }
            pendP[c][10] = 0.f; pendP[c][11] = 0.f;
            pendQ[c][10] = 0.f; pendQ[c][11] = 0.f;
            pendU[c][10] = 0.f; pendU[c][11] = 0.f;
            pendV[c][10] = 0.f; pendV[c][11] = 0.f;
        }

        // ---- 2x2 pool from registers (thread's col pair = 1 pooled output) ----
        if (doPool && k < (rps >> 1)) {
            float sa = u0save[0].x + u0save[0].z + u0save[1].x + u0save[1].z;
            float sb = u0save[0].y + u0save[0].w + u0save[1].y + u0save[1].w;
            int prow = (oy0 >> 1) + k;
            size_t o = (size_t)ch * halfS * halfS + (size_t)prow * halfS + lt;
            poolX[o] = 0.125f * (sa + sb);
            poolY[o] = 0.125f * (sa - sb);
        }

        // ---- stage next rows (vmcnt drain lives here, after all compute) ----
        if (k + 1 < NIT) {
            write_slot(sl ^ 1);
            if (k + 2 < NIT) issue(oy0 + 2 * (k + 2));
        }
        __syncthreads();
    }

    // ---- per-channel-subgroup reduction + atomic accumulate ----
    {
        int rw = (tpc < 64) ? tpc : 64;
        for (int off = rw >> 1; off > 0; off >>= 1) {
            ssum += __shfl_down(ssum, off);
            csum += __shfl_down(csum, off);
        }
        if ((lt & 63) == 0) {
            atomicAdd(&accum[ch], ssum);
            atomicAdd(&accum[96 + ch], csum);
        }
    }
}

// ------------- tiny hierarchical pool: P1 -> P2, P3, P4 -------------
__global__ __launch_bounds__(256)
void pool_pyramid_kernel(const float* __restrict__ p1x, const float* __restrict__ p1y,
                         float* __restrict__ p2x, float* __restrict__ p2y,
                         float* __restrict__ p3x, float* __restrict__ p3y,
                         float* __restrict__ p4x, float* __restrict__ p4y)
{
    const int tid  = threadIdx.x;
    const int ch   = blockIdx.y;                 // 96
    const int tile = blockIdx.x;                 // 16 tiles of 64x64 in 256x256
    const int ty0 = (tile >> 2) * 64, tx0 = (tile & 3) * 64;
    const int tr = tid >> 4, tc = tid & 15;      // 16x16 threads, each 4x4 input
    const int iy = ty0 + 4 * tr, ix = tx0 + 4 * tc;

    const float* X1 = p1x + (size_t)ch * 256 * 256;
    const float* Y1 = p1y + (size_t)ch * 256 * 256;

    float4 xr[4], yr[4];
    #pragma unroll
    for (int r = 0; r < 4; ++r) {
        xr[r] = *reinterpret_cast<const float4*>(X1 + (size_t)(iy + r) * 256 + ix);
        yr[r] = *reinterpret_cast<const float4*>(Y1 + (size_t)(iy + r) * 256 + ix);
    }

    // P2 (128x128): 2x2 outputs per thread
    float x200 = 0.25f * (xr[0].x + xr[0].y + xr[1].x + xr[1].y);
    float x201 = 0.25f * (xr[0].z + xr[0].w + xr[1].z + xr[1].w);
    float x210 = 0.25f * (xr[2].x + xr[2].y + xr[3].x + xr[3].y);
    float x211 = 0.25f * (xr[2].z + xr[2].w + xr[3].z + xr[3].w);
    float y200 = 0.25f * (yr[0].x + yr[0].y + yr[1].x + yr[1].y);
    float y201 = 0.25f * (yr[0].z + yr[0].w + yr[1].z + yr[1].w);
    float y210 = 0.25f * (yr[2].x + yr[2].y + yr[3].x + yr[3].y);
    float y211 = 0.25f * (yr[2].z + yr[2].w + yr[3].z + yr[3].w);
    {
        int oy = iy >> 1, ox = ix >> 1;
        float* bx = p2x + (size_t)ch * 128 * 128;
        float* by = p2y + (size_t)ch * 128 * 128;
        *reinterpret_cast<float2*>(bx + (size_t)oy * 128 + ox)       = make_float2(x200, x201);
        *reinterpret_cast<float2*>(bx + (size_t)(oy + 1) * 128 + ox) = make_float2(x210, x211);
        *reinterpret_cast<float2*>(by + (size_t)oy * 128 + ox)       = make_float2(y200, y201);
        *reinterpret_cast<float2*>(by + (size_t)(oy + 1) * 128 + ox) = make_float2(y210, y211);
    }

    // P3 (64x64): one output per thread
    float x3 = 0.25f * (x200 + x201 + x210 + x211);
    float y3 = 0.25f * (y200 + y201 + y210 + y211);
    p3x[(size_t)ch * 64 * 64 + (size_t)(iy >> 2) * 64 + (ix >> 2)] = x3;
    p3y[(size_t)ch * 64 * 64 + (size_t)(iy >> 2) * 64 + (ix >> 2)] = y3;

    // P4 (32x32): butterfly across tc (xor 1) and tr (xor 16)
    float x4 = x3 + __shfl_xor(x3, 1);
    float y4 = y3 + __shfl_xor(y3, 1);
    x4 += __shfl_xor(x4, 16);
    y4 += __shfl_xor(y4, 16);
    if (((tr | tc) & 1) == 0) {
        p4x[(size_t)ch * 32 * 32 + (size_t)(iy >> 3) * 32 + (ix >> 3)] = 0.25f * x4;
        p4y[(size_t)ch * 32 * 32 + (size_t)(iy >> 3) * 32 + (ix >> 3)] = 0.25f * y4;
    }
}

// ------------- Fused levels 1..4 kernel (no pooling, 630 blocks) -------------
__global__ __launch_bounds__(256)
void ssim_rest_kernel(const float* __restrict__ x1, const float* __restrict__ y1,
                      const float* __restrict__ x2, const float* __restrict__ y2,
                      const float* __restrict__ x3, const float* __restrict__ y3,
                      const float* __restrict__ x4, const float* __restrict__ y4,
                      float* __restrict__ accum, GWin gw)
{
    __shared__ float4 ab[2][2][264];

    const int bid = blockIdx.x;
    const int L = (bid >= 624) ? 3 : (bid >= 576) ? 2 : (bid >= 384) ? 1 : 0;
    const int off0 = (L == 0) ? 0 : (L == 1) ? 384 : (L == 2) ? 576 : 624;
    const int r = bid - off0;

    const int S      = (L == 0) ? 256 : (L == 1) ? 128 : (L == 2) ? 64 : 32;
    const int outS   = (L == 0) ? 246 : (L == 1) ? 118 : (L == 2) ? 54 : 22;
    const int rps    = (L == 0) ? 32  : (L == 1) ? 16  : (L == 2) ? 16 : 22;
    const int tpcLog = (L == 0) ? 7   : (L == 1) ? 6   : (L == 2) ? 5  : 4;
    const int stripsLog = (L == 0) ? 3 : (L == 1) ? 3 : (L == 2) ? 2 : 0;
    const float* Xl = (L == 0) ? x1 : (L == 1) ? x2 : (L == 2) ? x3 : x4;
    const float* Yl = (L == 0) ? y1 : (L == 1) ? y2 : (L == 2) ? y3 : y4;
    float* acc = accum + 192 * (L + 1);

    const int zidx  = r >> stripsLog;
    const int strip = r & ((1 << stripsLog) - 1);

    const int tid = threadIdx.x;
    const int tpc = 1 << tpcLog;
    const int lt  = tid & (tpc - 1);
    const int sub = tid >> tpcLog;
    const int ch  = zidx * (256 >> tpcLog) + sub;
    const int oy0 = strip * rps;
    const int gc  = 2 * lt;

    int rowsOut = outS - oy0; if (rowsOut > rps) rowsOut = rps;
    const int NIT = (rowsOut + 11) >> 1;

    const float* Xc = Xl + (size_t)ch * S * S;
    const float* Yc = Yl + (size_t)ch * S * S;

    float2 sx0, sy0, sx1, sy1;

    auto issue = [&](int baseRow) {
        int gr0 = baseRow;     if (gr0 > S - 1) gr0 = S - 1;
        int gr1 = baseRow + 1; if (gr1 > S - 1) gr1 = S - 1;
        sx0 = *reinterpret_cast<const float2*>(Xc + (size_t)gr0 * S + gc);
        sy0 = *reinterpret_cast<const float2*>(Yc + (size_t)gr0 * S + gc);
        sx1 = *reinterpret_cast<const float2*>(Xc + (size_t)gr1 * S + gc);
        sy1 = *reinterpret_cast<const float2*>(Yc + (size_t)gr1 * S + gc);
    };
    auto write_slot = [&](int sl) {
        ab[sl][0][tid] = make_float4(sx0.x + sy0.x, sx0.x - sy0.x,
                                     sx0.y + sy0.y, sx0.y - sy0.y);
        ab[sl][1][tid] = make_float4(sx1.x + sy1.x, sx1.x - sy1.x,
                                     sx1.y + sy1.y, sx1.y - sy1.y);
    };

    float pendP[2][12], pendQ[2][12], pendU[2][12], pendV[2][12];
    #pragma unroll
    for (int c = 0; c < 2; ++c)
        #pragma unroll
        for (int j = 0; j < 12; ++j) { pendP[c][j] = 0.f; pendQ[c][j] = 0.f; pendU[c][j] = 0.f; pendV[c][j] = 0.f; }

    float ssum = 0.f, csum = 0.f;
    const float C1x2 = 2e-4f, C2x2 = 1.8e-3f;
    const bool ok0 = gc < outS, ok1 = (gc + 1) < outS;

    if (tid < 8) {
        float4 z = make_float4(0.f, 0.f, 0.f, 0.f);
        ab[0][0][256 + tid] = z; ab[0][1][256 + tid] = z;
        ab[1][0][256 + tid] = z; ab[1][1][256 + tid] = z;
    }
    issue(oy0);
    write_slot(0);
    issue(oy0 + 2);
    __syncthreads();

    for (int k = 0; k < NIT; ++k) {
        const int sl = k & 1;

        float hP[2][2], hQ[2][2], hU[2][2], hV[2][2];
        #pragma unroll
        for (int r2 = 0; r2 < 2; ++r2) {
            const float4* bp = &ab[sl][r2][tid];
            float4 u[6];
            #pragma unroll
            for (int i = 0; i < 6; ++i) u[i] = bp[i];
            const float* v = reinterpret_cast<const float*>(u);
            float sqa[12], sqb[12];
            #pragma unroll
            for (int j = 0; j < 12; ++j) {
                float a = v[2 * j], b = v[2 * j + 1];
                sqa[j] = a * a; sqb[j] = b * b;
            }
            float P0 = 0.f, Q0 = 0.f, U0 = 0.f, V0 = 0.f;
            float P1 = 0.f, Q1 = 0.f, U1 = 0.f, V1 = 0.f;
            #pragma unroll
            for (int t = 0; t < 11; ++t) {
                float wt = gw.w[t];
                P0 = fmaf(wt, v[2 * t],     P0);
                Q0 = fmaf(wt, v[2 * t + 1], Q0);
                U0 = fmaf(wt, sqa[t],       U0);
                V0 = fmaf(wt, sqb[t],       V0);
                P1 = fmaf(wt, v[2 * t + 2], P1);
                Q1 = fmaf(wt, v[2 * t + 3], Q1);
                U1 = fmaf(wt, sqa[t + 1],   U1);
                V1 = fmaf(wt, sqb[t + 1],   V1);
            }
            hP[r2][0] = P0; hQ[r2][0] = Q0; hU[r2][0] = U0; hV[r2][0] = V0;
            hP[r2][1] = P1; hQ[r2][1] = Q1; hU[r2][1] = U1; hV[r2][1] = V1;
        }

        #pragma unroll
        for (int c = 0; c < 2; ++c) {
            #pragma unroll
            for (int j = 0; j <= 10; ++j) {
                float wt = gw.w[10 - j];
                pendP[c][j] = fmaf(wt, hP[0][c], pendP[c][j]);
                pendQ[c][j] = fmaf(wt, hQ[0][c], pendQ[c][j]);
                pendU[c][j] = fmaf(wt, hU[0][c], pendU[c][j]);
                pendV[c][j] = fmaf(wt, hV[0][c], pendV[c][j]);
            }
            #pragma unroll
            for (int j = 1; j <= 11; ++j) {
                float wt = gw.w[11 - j];
                pendP[c][j] = fmaf(wt, hP[1][c], pendP[c][j]);
                pendQ[c][j] = fmaf(wt, hQ[1][c], pendQ[c][j]);
                pendU[c][j] = fmaf(wt, hU[1][c], pendU[c][j]);
                pendV[c][j] = fmaf(wt, hV[1][c], pendV[c][j]);
            }
        }

        #pragma unroll
        for (int e = 0; e < 2; ++e) {
            int rel = 2 * k - 10 + e;
            bool rowok = (unsigned)rel < (unsigned)rowsOut;
            #pragma unroll
            for (int c = 0; c < 2; ++c) {
                float p = pendP[c][e], q = pendQ[c][e];
                float uu = pendU[c][e], vv = pendV[c][e];
                float p2 = p * p, q2 = q * q;
                float A = p2 - q2;
                float csn = (uu - vv - A) + C2x2;
                float csd = (uu + vv - p2 - q2) + C2x2;
                float cs  = csn * __builtin_amdgcn_rcpf(csd);
                float ss  = (A + C1x2) * __builtin_amdgcn_rcpf(p2 + q2 + C1x2) * cs;
                if (rowok && (c ? ok1 : ok0)) { ssum += ss; csum += cs; }
            }
        }

        #pragma unroll
        for (int c = 0; c < 2; ++c) {
            #pragma unroll
            for (int j = 0; j < 10; ++j) {
                pendP[c][j] = pendP[c][j + 2]; pendQ[c][j] = pendQ[c][j + 2];
                pendU[c][j] = pendU[c][j + 2]; pendV[c][j] = pendV[c][j + 2];
            }
            pendP[c][10] = 0.f; pendP[c][11] = 0.f;
            pendQ[c][10] = 0.f; pendQ[c][11] = 0.f;
            pendU[c][10] = 0.f; pendU[c][11] = 0.f;
            pendV[c][10] = 0.f; pendV[c][11] = 0.f;
        }

        if (k + 1 < NIT) {
            write_slot(sl ^ 1);
            if (k + 2 < NIT) issue(oy0 + 2 * (k + 2));
        }
        __syncthreads();
    }

    {
        int rw = (tpc < 64) ? tpc : 64;
        for (int off = rw >> 1; off > 0; off >>= 1) {
            ssum += __shfl_down(ssum, off);
            csum += __shfl_down(csum, off);
        }
        if ((lt & 63) == 0) {
            atomicAdd(&acc[ch], ssum);
            atomicAdd(&acc[96 + ch], csum);
        }
    }
}

__global__ void finalize_kernel(const float* __restrict__ accum, float* __restrict__ out)
{
    __shared__ float red[2];
    const int t = threadIdx.x;   // 128 threads
    const float w[5]   = {0.0448f, 0.2856f, 0.3001f, 0.2363f, 0.1333f};
    const float inv[5] = {1.f / (502.f * 502.f), 1.f / (246.f * 246.f),
                          1.f / (118.f * 118.f), 1.f / (54.f * 54.f),
                          1.f / (22.f * 22.f)};
    float ms = 0.f;
    if (t < 96) {
        ms = 1.f;
        #pragma unroll
        for (int l = 0; l < 5; ++l) {
            float v = (l < 4) ? accum[l * 192 + 96 + t] : accum[l * 192 + t];
            v *= inv[l];
            v = fmaxf(v, 0.f);
            ms *= powf(v, w[l]);
        }
    }
    for (int off = 32; off > 0; off >>= 1) ms += __shfl_down(ms, off);
    int wid = t >> 6, lane = t & 63;
    if (lane == 0) red[wid] = ms;
    __syncthreads();
    if (t == 0) out[0] = 1.f - (red[0] + red[1]) * (1.f / 96.f);
}

extern "C" void kernel_launch(void* const* d_in, const int* in_sizes, int n_in,
                              void* d_out, int out_size, void* d_ws, size_t ws_size,
                              hipStream_t stream)
{
    (void)in_sizes; (void)n_in; (void)out_size; (void)ws_size;
    const float* X = (const float*)d_in[0];
    const float* Y = (const float*)d_in[1];
    float* out = (float*)d_out;
    float* ws  = (float*)d_ws;

    // Gaussian window (size 11, sigma 1.5), normalized
    GWin gw;
    {
        double g[11], s = 0.0;
        for (int i = 0; i < 11; ++i) { double d = i - 5; g[i] = exp(-(d * d) / 4.5); s += g[i]; }
        for (int i = 0; i < 11; ++i) gw.w[i] = (float)(g[i] / s);
    }

    // workspace layout (floats): accum then pyramid buffers
    float* accum = ws;                 // L0 at +0, L1..L4 at +192*(L+1)
    size_t off = 1024;
    float* p1x = ws + off; off += (size_t)96 * 256 * 256;
    float* p1y = ws + off; off += (size_t)96 * 256 * 256;
    float* p2x = ws + off; off += (size_t)96 * 128 * 128;
    float* p2y = ws + off; off += (size_t)96 * 128 * 128;
    float* p3x = ws + off; off += (size_t)96 * 64 * 64;
    float* p3y = ws + off; off += (size_t)96 * 64 * 64;
    float* p4x = ws + off; off += (size_t)96 * 32 * 32;
    float* p4y = ws + off; off += (size_t)96 * 32 * 32;

    hipMemsetAsync(accum, 0, 5 * 192 * sizeof(float), stream);

    // L0: r15 kernel (writes P1 only), 8 strips x 96 channels
    ssim_rows_kernel<<<dim3(8, 1, 96), 256, 0, stream>>>(
        X, Y, p1x, p1y, accum, 512, 502, 1, 64, 8, gw);

    // P1 -> P2, P3, P4 (hierarchical, shfl butterflies)
    pool_pyramid_kernel<<<dim3(16, 96), 256, 0, stream>>>(
        p1x, p1y, p2x, p2y, p3x, p3y, p4x, p4y);

    // L1..L4 fused: 384 + 192 + 48 + 6 = 630 blocks
    ssim_rest_kernel<<<dim3(630), 256, 0, stream>>>(
        p1x, p1y, p2x, p2y, p3x, p3y, p4x, p4y, accum, gw);

    finalize_kernel<<<1, 128, 0, stream>>>(accum, out);
}